// Round 11
// baseline (209.276 us; speedup 1.0000x reference)
//
#include <hip/hip_runtime.h>
#include <math.h>

#define SEQ 4096
#define DIM 1024

typedef unsigned short u16;
typedef __attribute__((ext_vector_type(8))) short short8;     // 8 x bf16 (4 VGPRs)
typedef __attribute__((ext_vector_type(4))) float floatx4;    // MFMA accumulator
typedef __attribute__((ext_vector_type(4))) unsigned short us4;

__device__ __forceinline__ float bf2f(u16 u) {
    union { unsigned int i; float f; } c; c.i = ((unsigned int)u) << 16; return c.f;
}
__device__ __forceinline__ u16 f2bf(float f) {
    union { float f; unsigned int i; } c; c.f = f;
    return (u16)((c.i + 0x7fffu + ((c.i >> 16) & 1u)) >> 16);  // RNE
}
__device__ __forceinline__ void gload_lds16(const u16* g, u16* l) {
    __builtin_amdgcn_global_load_lds((const __attribute__((address_space(1))) void*)g,
                                     (__attribute__((address_space(3))) void*)l, 16, 0, 0);
}

// ---------------------------------------------------------------------------
// QKV GEMM (4-wave, proven R6 core): [Q|K] = x@[Wq|Wk] bf16 (Q scaled 1/32),
// V cols -> V^T bf16 (us4-packed). 128x128, BK=32, 3-stage pipeline,
// vmcnt(4), XOR-swizzled LDS (conflicts=0). Grid (32 row-bands, 24 col).
// ---------------------------------------------------------------------------
__global__ __launch_bounds__(256) void gemm_qkv(const u16* __restrict__ A,
                                                const u16* __restrict__ B,
                                                u16* __restrict__ QK,
                                                u16* __restrict__ VtOut) {
    const int row0 = blockIdx.x * 128;
    const int col0 = blockIdx.y * 128;

    __shared__ u16 As[3][4096];
    __shared__ u16 Bs[3][4096];

    const int tid  = threadIdx.x;
    const int wave = tid >> 6;
    const int lane = tid & 63;
    const int wm = wave & 1;
    const int wn = wave >> 1;

    const int s0 = wave * 128 + lane;
    const int s1 = s0 + 64;
    const int r0s = s0 >> 2, q0s = ((s0 & 3) ^ ((s0 >> 3) & 3)) * 8;
    const int r1s = s1 >> 2, q1s = ((s1 & 3) ^ ((s1 >> 3) & 3)) * 8;
    const u16* aP0 = A + (size_t)(row0 + r0s) * DIM + q0s;
    const u16* aP1 = A + (size_t)(row0 + r1s) * DIM + q1s;
    const u16* bP0 = B + (size_t)(col0 + r0s) * DIM + q0s;
    const u16* bP1 = B + (size_t)(col0 + r1s) * DIM + q1s;
    const int l0 = wave * 1024;

    floatx4 acc[4][4] = {};
    const int niter = DIM >> 5;   // 32
    const int frow = lane & 15;
    const int xq = (((lane >> 4) ^ ((frow >> 1) & 3))) * 8;

    gload_lds16(aP0, &As[0][l0]);
    gload_lds16(aP1, &As[0][l0 + 512]);
    gload_lds16(bP0, &Bs[0][l0]);
    gload_lds16(bP1, &Bs[0][l0 + 512]);
    aP0 += 32; aP1 += 32; bP0 += 32; bP1 += 32;
    gload_lds16(aP0, &As[1][l0]);
    gload_lds16(aP1, &As[1][l0 + 512]);
    gload_lds16(bP0, &Bs[1][l0]);
    gload_lds16(bP1, &Bs[1][l0 + 512]);
    aP0 += 32; aP1 += 32; bP0 += 32; bP1 += 32;

    auto compute_tile = [&](int c) {
        short8 af[4], bfr[4];
#pragma unroll
        for (int t = 0; t < 4; ++t) {
            af[t]  = *(const short8*)&As[c][(wm * 64 + t * 16 + frow) * 32 + xq];
            bfr[t] = *(const short8*)&Bs[c][(wn * 64 + t * 16 + frow) * 32 + xq];
        }
#pragma unroll
        for (int mt = 0; mt < 4; ++mt)
#pragma unroll
            for (int nt = 0; nt < 4; ++nt)
                acc[mt][nt] = __builtin_amdgcn_mfma_f32_16x16x32_bf16(
                    af[mt], bfr[nt], acc[mt][nt], 0, 0, 0);
    };

    int cur = 0, pre = 2;
    for (int it = 0; it < niter - 2; ++it) {
        asm volatile("s_waitcnt vmcnt(4)\n\ts_barrier" ::: "memory");
        short8 af[4], bfr[4];
#pragma unroll
        for (int t = 0; t < 4; ++t) {
            af[t]  = *(const short8*)&As[cur][(wm * 64 + t * 16 + frow) * 32 + xq];
            bfr[t] = *(const short8*)&Bs[cur][(wn * 64 + t * 16 + frow) * 32 + xq];
        }
        gload_lds16(aP0, &As[pre][l0]);
        gload_lds16(aP1, &As[pre][l0 + 512]);
        gload_lds16(bP0, &Bs[pre][l0]);
        gload_lds16(bP1, &Bs[pre][l0 + 512]);
        aP0 += 32; aP1 += 32; bP0 += 32; bP1 += 32;
#pragma unroll
        for (int mt = 0; mt < 4; ++mt)
#pragma unroll
            for (int nt = 0; nt < 4; ++nt)
                acc[mt][nt] = __builtin_amdgcn_mfma_f32_16x16x32_bf16(
                    af[mt], bfr[nt], acc[mt][nt], 0, 0, 0);
        cur = (cur == 2) ? 0 : cur + 1;
        pre = (pre == 2) ? 0 : pre + 1;
    }
    asm volatile("s_waitcnt vmcnt(4)\n\ts_barrier" ::: "memory");
    compute_tile(cur);
    cur = (cur == 2) ? 0 : cur + 1;
    asm volatile("s_waitcnt vmcnt(0)\n\ts_barrier" ::: "memory");
    compute_tile(cur);

    const int cr = (lane >> 4) * 4;
    const int cc = lane & 15;
    if (col0 >= 2048) {
        // V columns -> V^T bf16: 4 consecutive regs = 4 consecutive rows.
#pragma unroll
        for (int mt = 0; mt < 4; ++mt)
#pragma unroll
            for (int nt = 0; nt < 4; ++nt) {
                const int row = row0 + wm * 64 + mt * 16 + cr;
                const int col = (col0 - 2048) + wn * 64 + nt * 16 + cc;
                us4 o = { f2bf(acc[mt][nt][0]), f2bf(acc[mt][nt][1]),
                          f2bf(acc[mt][nt][2]), f2bf(acc[mt][nt][3]) };
                *(us4*)&VtOut[(size_t)col * SEQ + row] = o;
            }
    } else {
        const float sc = (col0 < 1024) ? 0.03125f : 1.0f;
#pragma unroll
        for (int mt = 0; mt < 4; ++mt)
#pragma unroll
            for (int nt = 0; nt < 4; ++nt)
#pragma unroll
                for (int r = 0; r < 4; ++r) {
                    const int row = row0 + wm * 64 + mt * 16 + cr + r;
                    const int col = col0 + wn * 64 + nt * 16 + cc;
                    QK[(size_t)row * 2048 + col] = f2bf(acc[mt][nt][r] * sc);
                }
    }
}

// ---------------------------------------------------------------------------
// R11 8-wave (512-thread) GEMM core for scores & PV. 128x128 tile, BK=32,
// 3-stage LDS pipeline; waves 0-3 stage A (2 loads/tile), 4-7 stage B ->
// steady s_waitcnt vmcnt(2). Wave (wm=w&1, wn=w>>1) computes 64x32 via
// 4x2 MFMA. 2.06 blocks/CU x 8 waves = ~16.5 waves/CU (2x R9) for stall
// cover; __launch_bounds__(512,4) caps VGPR<=128 so 2 blocks/CU fit.
// SCORES=1: early-exit col0>row0; epilogue e=exp(s) (no-max: logits~N(0,1),
//   shift-invariant softmax), mask j>i, E bf16, atomicAdd row sums.
// SCORES=0 (PV): banded grid (80,8): u decodes (row-tile, k-chunk);
//   epilogue atomicAdds acc/Lsum into O (zeroed by prep).
// ---------------------------------------------------------------------------
template <int SCORES>
__global__ __launch_bounds__(512, 4) void gemm_att(const u16* __restrict__ A,
                                                   const u16* __restrict__ B,
                                                   void* __restrict__ Cv,
                                                   float* __restrict__ Lsum,
                                                   int lda, int ldb) {
    int row0, col0, kbeg = 0, kend;
    if (SCORES) {
        col0 = blockIdx.x * 128;
        row0 = blockIdx.y * 128;
        if (col0 > row0) return;
        kend = DIM;
    } else {
        const int u = blockIdx.x;  // 0..79
        col0 = blockIdx.y * 128;
        int r, c;
        if (u < 32)      { c = 0; r = u; }
        else if (u < 56) { c = 1; r = u - 24; }
        else if (u < 72) { c = 2; r = u - 40; }
        else             { c = 3; r = u - 48; }
        row0 = r * 128;
        kbeg = c << 10;
        kend = min(kbeg + 1024, row0 + 128);
    }

    __shared__ u16 As[3][4096];
    __shared__ u16 Bs[3][4096];

    const int tid  = threadIdx.x;
    const int wave = tid >> 6;     // 0..7
    const int lane = tid & 63;
    const int wm = wave & 1;       // 64-row half
    const int wn = wave >> 1;      // 32-col quarter (0..3)

    // staging: waves 0-3 stage A slots, waves 4-7 stage B slots.
    const int sw = wave & 3;
    const int s0 = sw * 128 + lane;
    const int s1 = s0 + 64;
    const int r0s = s0 >> 2, q0s = ((s0 & 3) ^ ((s0 >> 3) & 3)) * 8;
    const int r1s = s1 >> 2, q1s = ((s1 & 3) ^ ((s1 >> 3) & 3)) * 8;
    const bool isA = wave < 4;
    const u16* p0 = isA ? A + (size_t)(row0 + r0s) * lda + kbeg + q0s
                        : B + (size_t)(col0 + r0s) * ldb + kbeg + q0s;
    const u16* p1 = isA ? A + (size_t)(row0 + r1s) * lda + kbeg + q1s
                        : B + (size_t)(col0 + r1s) * ldb + kbeg + q1s;
    const int o0 = s0 * 8;   // LDS element offset of slot s0
    const int o1 = o0 + 512;

    floatx4 acc[4][2] = {};
    const int niter = (kend - kbeg) >> 5;   // >= 4
    const int frow = lane & 15;
    const int xq = (((lane >> 4) ^ ((frow >> 1) & 3))) * 8;

    {
        u16* d0 = isA ? &As[0][0] : &Bs[0][0];
        gload_lds16(p0, d0 + o0);
        gload_lds16(p1, d0 + o1);
        p0 += 32; p1 += 32;
        u16* d1 = isA ? &As[1][0] : &Bs[1][0];
        gload_lds16(p0, d1 + o0);
        gload_lds16(p1, d1 + o1);
        p0 += 32; p1 += 32;
    }

    auto compute_tile = [&](int c) {
        short8 af[4], bfr[2];
#pragma unroll
        for (int t = 0; t < 4; ++t)
            af[t] = *(const short8*)&As[c][(wm * 64 + t * 16 + frow) * 32 + xq];
#pragma unroll
        for (int t = 0; t < 2; ++t)
            bfr[t] = *(const short8*)&Bs[c][(wn * 32 + t * 16 + frow) * 32 + xq];
#pragma unroll
        for (int mt = 0; mt < 4; ++mt)
#pragma unroll
            for (int nt = 0; nt < 2; ++nt)
                acc[mt][nt] = __builtin_amdgcn_mfma_f32_16x16x32_bf16(
                    af[mt], bfr[nt], acc[mt][nt], 0, 0, 0);
    };

    int cur = 0, pre = 2;
    for (int it = 0; it < niter - 2; ++it) {
        asm volatile("s_waitcnt vmcnt(2)\n\ts_barrier" ::: "memory");
        short8 af[4], bfr[2];
#pragma unroll
        for (int t = 0; t < 4; ++t)
            af[t] = *(const short8*)&As[cur][(wm * 64 + t * 16 + frow) * 32 + xq];
#pragma unroll
        for (int t = 0; t < 2; ++t)
            bfr[t] = *(const short8*)&Bs[cur][(wn * 32 + t * 16 + frow) * 32 + xq];
        u16* dp = isA ? &As[pre][0] : &Bs[pre][0];
        gload_lds16(p0, dp + o0);
        gload_lds16(p1, dp + o1);
        p0 += 32; p1 += 32;
#pragma unroll
        for (int mt = 0; mt < 4; ++mt)
#pragma unroll
            for (int nt = 0; nt < 2; ++nt)
                acc[mt][nt] = __builtin_amdgcn_mfma_f32_16x16x32_bf16(
                    af[mt], bfr[nt], acc[mt][nt], 0, 0, 0);
        cur = (cur == 2) ? 0 : cur + 1;
        pre = (pre == 2) ? 0 : pre + 1;
    }
    asm volatile("s_waitcnt vmcnt(2)\n\ts_barrier" ::: "memory");
    compute_tile(cur);
    cur = (cur == 2) ? 0 : cur + 1;
    asm volatile("s_waitcnt vmcnt(0)\n\ts_barrier" ::: "memory");
    compute_tile(cur);

    const int cr = (lane >> 4) * 4;
    const int cc = lane & 15;
    if (SCORES) {
        u16* E = (u16*)Cv;
#pragma unroll
        for (int mt = 0; mt < 4; ++mt) {
#pragma unroll
            for (int r = 0; r < 4; ++r) {
                const int grow = row0 + wm * 64 + mt * 16 + cr + r;
                float rowsum = 0.f;
#pragma unroll
                for (int nt = 0; nt < 2; ++nt) {
                    const int gcol = col0 + wn * 32 + nt * 16 + cc;
                    const float e = (gcol <= grow) ? __expf(acc[mt][nt][r]) : 0.f;
                    rowsum += e;
                    E[(size_t)grow * SEQ + gcol] = f2bf(e);
                }
                rowsum += __shfl_xor(rowsum, 1);
                rowsum += __shfl_xor(rowsum, 2);
                rowsum += __shfl_xor(rowsum, 4);
                rowsum += __shfl_xor(rowsum, 8);
                if (cc == 0) atomicAdd(&Lsum[grow], rowsum);
            }
        }
    } else {
        float* O = (float*)Cv;
#pragma unroll
        for (int mt = 0; mt < 4; ++mt)
#pragma unroll
            for (int r = 0; r < 4; ++r) {
                const int grow = row0 + wm * 64 + mt * 16 + cr + r;
                const float invl = 1.0f / Lsum[grow];
#pragma unroll
                for (int nt = 0; nt < 2; ++nt) {
                    const int col = col0 + wn * 32 + nt * 16 + cc;
                    atomicAdd(&O[(size_t)grow * DIM + col], acc[mt][nt][r] * invl);
                }
            }
    }
}

// ---------------------------------------------------------------------------
// prep, linear grid of 8192 blocks:
//   [0,4096):    x fp32 -> bf16 flat cast
//   [4096,7168): W [k][n] fp32 -> bf16 [n][k], stacked [3072][1024]
//   [7168,8192): zero O; first 4 blocks also zero Lsum
// ---------------------------------------------------------------------------
__global__ __launch_bounds__(256) void prep(const float* __restrict__ x,
                                            const float* __restrict__ W0,
                                            const float* __restrict__ W1,
                                            const float* __restrict__ W2,
                                            u16* __restrict__ xb,
                                            u16* __restrict__ Wt,
                                            float* __restrict__ O,
                                            float* __restrict__ Lsum) {
    __shared__ float tile[32][33];
    const int b = blockIdx.x;
    const int tid = threadIdx.x;
    if (b < 4096) {
        const size_t i = ((size_t)b * 256 + tid) * 4;
        const float4 v = *(const float4*)(x + i);
        us4 o = { f2bf(v.x), f2bf(v.y), f2bf(v.z), f2bf(v.w) };
        *(us4*)(xb + i) = o;
    } else if (b < 7168) {
        const int t = b - 4096;
        const int z = t >> 10;
        const int idx = t & 1023;
        const float* W = (z == 0) ? W0 : (z == 1) ? W1 : W2;
        u16* out = Wt + (size_t)z * DIM * DIM;
        const int bx = (idx & 31) * 32;  // n block
        const int by = (idx >> 5) * 32;  // k block
        const int tx = tid & 31;
        const int ty = (tid >> 5) * 4;
#pragma unroll
        for (int r = 0; r < 4; ++r)
            tile[ty + r][tx] = W[(size_t)(by + ty + r) * DIM + bx + tx];
        __syncthreads();
#pragma unroll
        for (int r = 0; r < 4; ++r)
            out[(size_t)(bx + ty + r) * DIM + by + tx] = f2bf(tile[tx][ty + r]);
    } else {
        const int t = b - 7168;  // 0..1023
        const size_t i = ((size_t)t * 256 + tid) * 4;
        *(float4*)(O + i) = make_float4(0.f, 0.f, 0.f, 0.f);
        if (t < 4) *(float4*)(Lsum + (size_t)(t * 256 + tid) * 4) =
            make_float4(0.f, 0.f, 0.f, 0.f);
    }
}

extern "C" void kernel_launch(void* const* d_in, const int* in_sizes, int n_in,
                              void* d_out, int out_size, void* d_ws, size_t ws_size,
                              hipStream_t stream) {
    const float* x  = (const float*)d_in[0];
    const float* Wq = (const float*)d_in[1];
    const float* Wk = (const float*)d_in[2];
    const float* Wv = (const float*)d_in[3];

    // ws: xb 8MB | Wt 6MB | QK 16MB | Vt 8MB | E 32MB | Lsum 16KB  = 70 MB
    u16* xb   = (u16*)d_ws;
    u16* Wt   = xb + (size_t)SEQ * DIM;
    u16* QK   = Wt + (size_t)3072 * DIM;
    u16* Vt   = QK + (size_t)SEQ * 2048;
    u16* E    = Vt + (size_t)DIM * SEQ;
    float* Lsum = (float*)(E + (size_t)SEQ * SEQ);

    prep<<<8192, 256, 0, stream>>>(x, Wq, Wk, Wv, xb, Wt, (float*)d_out, Lsum);

    // [Q|K] bf16 + V^T bf16. 768 blocks, 4-wave.
    gemm_qkv<<<dim3(32, 24), 256, 0, stream>>>(xb, Wt, QK, Vt);

    // E = exp(Q @ K^T) + row sums. (32,32) early-exit, 528 active, 8-wave.
    gemm_att<1><<<dim3(32, 32), 512, 0, stream>>>(
        QK, QK + 1024, E, Lsum, 2048, 2048);

    // O += (E @ Vt^T)/Lsum. Banded split-K (80 bands, 8 col tiles), 8-wave.
    gemm_att<0><<<dim3(80, 8), 512, 0, stream>>>(
        E, Vt, d_out, Lsum, SEQ, SEQ);
}

// Round 12
// 205.990 us; speedup vs baseline: 1.0159x; 1.0159x over previous
//
#include <hip/hip_runtime.h>
#include <math.h>

#define SEQ 4096
#define DIM 1024

typedef unsigned short u16;
typedef __attribute__((ext_vector_type(8))) short short8;     // 8 x bf16 (4 VGPRs)
typedef __attribute__((ext_vector_type(4))) float floatx4;    // MFMA accumulator
typedef __attribute__((ext_vector_type(4))) unsigned short us4;

__device__ __forceinline__ float bf2f(u16 u) {
    union { unsigned int i; float f; } c; c.i = ((unsigned int)u) << 16; return c.f;
}
__device__ __forceinline__ u16 f2bf(float f) {
    union { float f; unsigned int i; } c; c.f = f;
    return (u16)((c.i + 0x7fffu + ((c.i >> 16) & 1u)) >> 16);  // RNE
}
__device__ __forceinline__ void gload_lds16(const u16* g, u16* l) {
    __builtin_amdgcn_global_load_lds((const __attribute__((address_space(1))) void*)g,
                                     (__attribute__((address_space(3))) void*)l, 16, 0, 0);
}

// ---------------------------------------------------------------------------
// QKV GEMM (4-wave, proven R6 core, unchanged from R9): [Q|K] = x@[Wq|Wk]
// bf16 (Q scaled 1/32), V cols -> V^T bf16. 128x128, BK=32, 3-stage, vmcnt(4).
// ---------------------------------------------------------------------------
__global__ __launch_bounds__(256) void gemm_qkv(const u16* __restrict__ A,
                                                const u16* __restrict__ B,
                                                u16* __restrict__ QK,
                                                u16* __restrict__ VtOut) {
    const int row0 = blockIdx.x * 128;
    const int col0 = blockIdx.y * 128;

    __shared__ u16 As[3][4096];
    __shared__ u16 Bs[3][4096];

    const int tid  = threadIdx.x;
    const int wave = tid >> 6;
    const int lane = tid & 63;
    const int wm = wave & 1;
    const int wn = wave >> 1;

    const int s0 = wave * 128 + lane;
    const int s1 = s0 + 64;
    const int r0s = s0 >> 2, q0s = ((s0 & 3) ^ ((s0 >> 3) & 3)) * 8;
    const int r1s = s1 >> 2, q1s = ((s1 & 3) ^ ((s1 >> 3) & 3)) * 8;
    const u16* aP0 = A + (size_t)(row0 + r0s) * DIM + q0s;
    const u16* aP1 = A + (size_t)(row0 + r1s) * DIM + q1s;
    const u16* bP0 = B + (size_t)(col0 + r0s) * DIM + q0s;
    const u16* bP1 = B + (size_t)(col0 + r1s) * DIM + q1s;
    const int l0 = wave * 1024;

    floatx4 acc[4][4] = {};
    const int niter = DIM >> 5;   // 32
    const int frow = lane & 15;
    const int xq = (((lane >> 4) ^ ((frow >> 1) & 3))) * 8;

    gload_lds16(aP0, &As[0][l0]);
    gload_lds16(aP1, &As[0][l0 + 512]);
    gload_lds16(bP0, &Bs[0][l0]);
    gload_lds16(bP1, &Bs[0][l0 + 512]);
    aP0 += 32; aP1 += 32; bP0 += 32; bP1 += 32;
    gload_lds16(aP0, &As[1][l0]);
    gload_lds16(aP1, &As[1][l0 + 512]);
    gload_lds16(bP0, &Bs[1][l0]);
    gload_lds16(bP1, &Bs[1][l0 + 512]);
    aP0 += 32; aP1 += 32; bP0 += 32; bP1 += 32;

    auto compute_tile = [&](int c) {
        short8 af[4], bfr[4];
#pragma unroll
        for (int t = 0; t < 4; ++t) {
            af[t]  = *(const short8*)&As[c][(wm * 64 + t * 16 + frow) * 32 + xq];
            bfr[t] = *(const short8*)&Bs[c][(wn * 64 + t * 16 + frow) * 32 + xq];
        }
#pragma unroll
        for (int mt = 0; mt < 4; ++mt)
#pragma unroll
            for (int nt = 0; nt < 4; ++nt)
                acc[mt][nt] = __builtin_amdgcn_mfma_f32_16x16x32_bf16(
                    af[mt], bfr[nt], acc[mt][nt], 0, 0, 0);
    };

    int cur = 0, pre = 2;
    for (int it = 0; it < niter - 2; ++it) {
        asm volatile("s_waitcnt vmcnt(4)\n\ts_barrier" ::: "memory");
        short8 af[4], bfr[4];
#pragma unroll
        for (int t = 0; t < 4; ++t) {
            af[t]  = *(const short8*)&As[cur][(wm * 64 + t * 16 + frow) * 32 + xq];
            bfr[t] = *(const short8*)&Bs[cur][(wn * 64 + t * 16 + frow) * 32 + xq];
        }
        gload_lds16(aP0, &As[pre][l0]);
        gload_lds16(aP1, &As[pre][l0 + 512]);
        gload_lds16(bP0, &Bs[pre][l0]);
        gload_lds16(bP1, &Bs[pre][l0 + 512]);
        aP0 += 32; aP1 += 32; bP0 += 32; bP1 += 32;
#pragma unroll
        for (int mt = 0; mt < 4; ++mt)
#pragma unroll
            for (int nt = 0; nt < 4; ++nt)
                acc[mt][nt] = __builtin_amdgcn_mfma_f32_16x16x32_bf16(
                    af[mt], bfr[nt], acc[mt][nt], 0, 0, 0);
        cur = (cur == 2) ? 0 : cur + 1;
        pre = (pre == 2) ? 0 : pre + 1;
    }
    asm volatile("s_waitcnt vmcnt(4)\n\ts_barrier" ::: "memory");
    compute_tile(cur);
    cur = (cur == 2) ? 0 : cur + 1;
    asm volatile("s_waitcnt vmcnt(0)\n\ts_barrier" ::: "memory");
    compute_tile(cur);

    const int cr = (lane >> 4) * 4;
    const int cc = lane & 15;
    if (col0 >= 2048) {
#pragma unroll
        for (int mt = 0; mt < 4; ++mt)
#pragma unroll
            for (int nt = 0; nt < 4; ++nt) {
                const int row = row0 + wm * 64 + mt * 16 + cr;
                const int col = (col0 - 2048) + wn * 64 + nt * 16 + cc;
                us4 o = { f2bf(acc[mt][nt][0]), f2bf(acc[mt][nt][1]),
                          f2bf(acc[mt][nt][2]), f2bf(acc[mt][nt][3]) };
                *(us4*)&VtOut[(size_t)col * SEQ + row] = o;
            }
    } else {
        const float sc = (col0 < 1024) ? 0.03125f : 1.0f;
#pragma unroll
        for (int mt = 0; mt < 4; ++mt)
#pragma unroll
            for (int nt = 0; nt < 4; ++nt)
#pragma unroll
                for (int r = 0; r < 4; ++r) {
                    const int row = row0 + wm * 64 + mt * 16 + cr + r;
                    const int col = col0 + wn * 64 + nt * 16 + cc;
                    QK[(size_t)row * 2048 + col] = f2bf(acc[mt][nt][r] * sc);
                }
    }
}

// ---------------------------------------------------------------------------
// R12 BK=64 GEMM for scores & PV. 128x128 tile, BK=64, 4 waves, 2-stage
// double buffer (2 x 32KB = 64KB -> 2 blocks/CU, matching the grid's
// residency). Halves the iteration count (the ~1000-cyc fixed per-iteration
// stall) vs BK=32. Per iteration: [vmcnt(0)+barrier] -> 16 ds_read_b128 ->
// 8 DMA issues (next tile) -> 32 MFMA. The vmcnt(0) drains loads issued one
// full (double-length) iteration earlier. 2-stage safety: loads for tile
// it+1 target buf (it+1)&1, last read at iter it-1; the barrier proves all
// waves finished those reads (their MFMAs depended on them).
// LDS layout: row = 64 k = 8 x16B chunks; chunk q at slot q ^ (row&7) ->
// fragment-read bank group = chunk only, <=2 lanes/group/phase = free.
// SCORES=1: compact triangular grid (528); epilogue e=exp(s) (no-max trick),
//   mask j>i, E bf16, atomicAdd row sums into Lsum.
// SCORES=0 (PV): grid (8 col-tiles, 80 bands); epilogue atomicAdds
//   acc/Lsum[row] into O (zeroed by prep).
// ---------------------------------------------------------------------------
template <int SCORES>
__global__ __launch_bounds__(256) void gemm_att64(const u16* __restrict__ A,
                                                  const u16* __restrict__ B,
                                                  void* __restrict__ Cv,
                                                  float* __restrict__ Lsum,
                                                  int lda, int ldb) {
    int row0, col0, kbeg = 0, kend;
    if (SCORES) {
        const int t = blockIdx.x;  // 0..527 -> (by, bx<=by)
        int by = (int)((sqrtf(8.0f * t + 1.0f) - 1.0f) * 0.5f);
        while ((by + 1) * (by + 2) / 2 <= t) ++by;
        while (by * (by + 1) / 2 > t) --by;
        const int bx = t - by * (by + 1) / 2;
        row0 = by * 128;
        col0 = bx * 128;
        kend = DIM;
    } else {
        col0 = blockIdx.x * 128;
        const int u = blockIdx.y;  // 0..79
        int r, c;
        if (u < 32)      { c = 0; r = u; }
        else if (u < 56) { c = 1; r = u - 24; }
        else if (u < 72) { c = 2; r = u - 40; }
        else             { c = 3; r = u - 48; }
        row0 = r * 128;
        kbeg = c << 10;
        kend = min(kbeg + 1024, row0 + 128);
    }

    __shared__ u16 As[2][8192];  // 2 x 16KB (128 rows x 64 k)
    __shared__ u16 Bs[2][8192];

    const int tid  = threadIdx.x;
    const int wave = tid >> 6;
    const int lane = tid & 63;
    const int wm = wave & 1;
    const int wn = wave >> 1;

    // staging: 1024 16B-slots per operand tile; wave covers slots
    // wave*256 + j*64 + lane, j=0..3. slot s: row=s>>3, chunk=(s&7)^(row&7).
    const u16* aP[4];
    const u16* bP[4];
    int dOff[4];
#pragma unroll
    for (int j = 0; j < 4; ++j) {
        const int s = wave * 256 + j * 64 + lane;
        const int r = s >> 3;
        const int q = (s & 7) ^ (r & 7);
        aP[j] = A + (size_t)(row0 + r) * lda + kbeg + q * 8;
        bP[j] = B + (size_t)(col0 + r) * ldb + kbeg + q * 8;
        dOff[j] = s * 8;
    }

    floatx4 acc[4][4] = {};
    const int niter = (kend - kbeg) >> 6;   // scores: 16; PV: 2..16
    const int frow = lane & 15;
    const int grp  = lane >> 4;

    // prologue: tile 0 -> buf 0 (8 loads/wave)
#pragma unroll
    for (int j = 0; j < 4; ++j) {
        gload_lds16(aP[j], &As[0][dOff[j]]);
        gload_lds16(bP[j], &Bs[0][dOff[j]]);
        aP[j] += 64; bP[j] += 64;
    }

    for (int it = 0; it < niter; ++it) {
        asm volatile("s_waitcnt vmcnt(0)\n\ts_barrier" ::: "memory");
        const int cur = it & 1;
        // fragment reads: both 32-wide k-steps, conflict-free swizzle
        short8 af[2][4], bfr[2][4];
#pragma unroll
        for (int ks = 0; ks < 2; ++ks)
#pragma unroll
            for (int t = 0; t < 4; ++t) {
                const int ar = wm * 64 + t * 16 + frow;
                const int ca = (ks * 4 + grp) ^ (ar & 7);
                af[ks][t] = *(const short8*)&As[cur][ar * 64 + ca * 8];
                const int br = wn * 64 + t * 16 + frow;
                const int cb = (ks * 4 + grp) ^ (br & 7);
                bfr[ks][t] = *(const short8*)&Bs[cur][br * 64 + cb * 8];
            }
        // prefetch tile it+1 into the other buffer (safe per barrier above)
        if (it + 1 < niter) {
            const int nxt = cur ^ 1;
#pragma unroll
            for (int j = 0; j < 4; ++j) {
                gload_lds16(aP[j], &As[nxt][dOff[j]]);
                gload_lds16(bP[j], &Bs[nxt][dOff[j]]);
                aP[j] += 64; bP[j] += 64;
            }
        }
#pragma unroll
        for (int ks = 0; ks < 2; ++ks)
#pragma unroll
            for (int mt = 0; mt < 4; ++mt)
#pragma unroll
                for (int nt = 0; nt < 4; ++nt)
                    acc[mt][nt] = __builtin_amdgcn_mfma_f32_16x16x32_bf16(
                        af[ks][mt], bfr[ks][nt], acc[mt][nt], 0, 0, 0);
    }

    // epilogue: C/D layout col=lane&15, row=(lane>>4)*4+reg
    const int cr = (lane >> 4) * 4;
    const int cc = lane & 15;
    if (SCORES) {
        u16* E = (u16*)Cv;
#pragma unroll
        for (int mt = 0; mt < 4; ++mt) {
#pragma unroll
            for (int r = 0; r < 4; ++r) {
                const int grow = row0 + wm * 64 + mt * 16 + cr + r;
                float rowsum = 0.f;
#pragma unroll
                for (int nt = 0; nt < 4; ++nt) {
                    const int gcol = col0 + wn * 64 + nt * 16 + cc;
                    const float e = (gcol <= grow) ? __expf(acc[mt][nt][r]) : 0.f;
                    rowsum += e;
                    E[(size_t)grow * SEQ + gcol] = f2bf(e);
                }
                rowsum += __shfl_xor(rowsum, 1);
                rowsum += __shfl_xor(rowsum, 2);
                rowsum += __shfl_xor(rowsum, 4);
                rowsum += __shfl_xor(rowsum, 8);
                if (cc == 0) atomicAdd(&Lsum[grow], rowsum);
            }
        }
    } else {
        float* O = (float*)Cv;
#pragma unroll
        for (int mt = 0; mt < 4; ++mt)
#pragma unroll
            for (int r = 0; r < 4; ++r) {
                const int grow = row0 + wm * 64 + mt * 16 + cr + r;
                const float invl = 1.0f / Lsum[grow];
#pragma unroll
                for (int nt = 0; nt < 4; ++nt) {
                    const int col = col0 + wn * 64 + nt * 16 + cc;
                    atomicAdd(&O[(size_t)grow * DIM + col], acc[mt][nt][r] * invl);
                }
            }
    }
}

// ---------------------------------------------------------------------------
// prep, linear grid of 8192 blocks:
//   [0,4096):    x fp32 -> bf16 flat cast
//   [4096,7168): W [k][n] fp32 -> bf16 [n][k], stacked [3072][1024]
//   [7168,8192): zero O; first 4 blocks also zero Lsum
// ---------------------------------------------------------------------------
__global__ __launch_bounds__(256) void prep(const float* __restrict__ x,
                                            const float* __restrict__ W0,
                                            const float* __restrict__ W1,
                                            const float* __restrict__ W2,
                                            u16* __restrict__ xb,
                                            u16* __restrict__ Wt,
                                            float* __restrict__ O,
                                            float* __restrict__ Lsum) {
    __shared__ float tile[32][33];
    const int b = blockIdx.x;
    const int tid = threadIdx.x;
    if (b < 4096) {
        const size_t i = ((size_t)b * 256 + tid) * 4;
        const float4 v = *(const float4*)(x + i);
        us4 o = { f2bf(v.x), f2bf(v.y), f2bf(v.z), f2bf(v.w) };
        *(us4*)(xb + i) = o;
    } else if (b < 7168) {
        const int t = b - 4096;
        const int z = t >> 10;
        const int idx = t & 1023;
        const float* W = (z == 0) ? W0 : (z == 1) ? W1 : W2;
        u16* out = Wt + (size_t)z * DIM * DIM;
        const int bx = (idx & 31) * 32;  // n block
        const int by = (idx >> 5) * 32;  // k block
        const int tx = tid & 31;
        const int ty = (tid >> 5) * 4;
#pragma unroll
        for (int r = 0; r < 4; ++r)
            tile[ty + r][tx] = W[(size_t)(by + ty + r) * DIM + bx + tx];
        __syncthreads();
#pragma unroll
        for (int r = 0; r < 4; ++r)
            out[(size_t)(bx + ty + r) * DIM + by + tx] = f2bf(tile[tx][ty + r]);
    } else {
        const int t = b - 7168;  // 0..1023
        const size_t i = ((size_t)t * 256 + tid) * 4;
        *(float4*)(O + i) = make_float4(0.f, 0.f, 0.f, 0.f);
        if (t < 4) *(float4*)(Lsum + (size_t)(t * 256 + tid) * 4) =
            make_float4(0.f, 0.f, 0.f, 0.f);
    }
}

extern "C" void kernel_launch(void* const* d_in, const int* in_sizes, int n_in,
                              void* d_out, int out_size, void* d_ws, size_t ws_size,
                              hipStream_t stream) {
    const float* x  = (const float*)d_in[0];
    const float* Wq = (const float*)d_in[1];
    const float* Wk = (const float*)d_in[2];
    const float* Wv = (const float*)d_in[3];

    // ws: xb 8MB | Wt 6MB | QK 16MB | Vt 8MB | E 32MB | Lsum 16KB  = 70 MB
    u16* xb   = (u16*)d_ws;
    u16* Wt   = xb + (size_t)SEQ * DIM;
    u16* QK   = Wt + (size_t)3072 * DIM;
    u16* Vt   = QK + (size_t)SEQ * 2048;
    u16* E    = Vt + (size_t)DIM * SEQ;
    float* Lsum = (float*)(E + (size_t)SEQ * SEQ);

    prep<<<8192, 256, 0, stream>>>(x, Wq, Wk, Wv, xb, Wt, (float*)d_out, Lsum);

    // [Q|K] bf16 + V^T bf16. 768 blocks, 4-wave, BK=32 (3 blocks/CU).
    gemm_qkv<<<dim3(32, 24), 256, 0, stream>>>(xb, Wt, QK, Vt);

    // E = exp(Q @ K^T) + row sums. Compact triangular 528 blocks, BK=64.
    gemm_att64<1><<<528, 256, 0, stream>>>(QK, QK + 1024, E, Lsum, 2048, 2048);

    // O += (E @ Vt^T)/Lsum. Banded split-K (8 col tiles, 80 bands), BK=64.
    gemm_att64<0><<<dim3(8, 80), 256, 0, stream>>>(E, Vt, d_out, Lsum, SEQ, SEQ);
}